// Round 7
// baseline (278.544 us; speedup 1.0000x reference)
//
#include <hip/hip_runtime.h>

// TransformerBlock on MI355X (gfx950).
// v16: deep-pipeline GEMM skeleton (T3+T4+T5 port) for in-proj and GeGLU.
// 256x128 tiles, 512 threads (8 waves, 4m x 2n, per-wave 64x64 = unchanged
// fragment code), BK=32, FOUR-deep LDS tile ring (96KB), one s_barrier per
// phase, counted s_waitcnt vmcnt(6) (tiles g+1,g+2 always in flight, no
// drain until tail), stage tile g+3 after the barrier, setprio around the
// 16-MFMA cluster. Out-proj keeps v15 bt64; attn14/prep/LNs unchanged.

typedef __bf16 bf16;
typedef bf16 bf16x8 __attribute__((ext_vector_type(8)));
typedef bf16 bf16x4 __attribute__((ext_vector_type(4)));
typedef float f32x4 __attribute__((ext_vector_type(4)));
typedef float f32x16 __attribute__((ext_vector_type(16)));

#define EMB 1024
#define SEQ 2048
#define NTOK 4096
#define NH 16
#define HD 64

__device__ __forceinline__ f32x4 mfma16(bf16x8 a, bf16x8 b, f32x4 c) {
  return __builtin_amdgcn_mfma_f32_16x16x32_bf16(a, b, c, 0, 0, 0);
}
__device__ __forceinline__ f32x16 mfma32(bf16x8 a, bf16x8 b, f32x16 c) {
  return __builtin_amdgcn_mfma_f32_32x32x16_bf16(a, b, c, 0, 0, 0);
}

__device__ __forceinline__ void gll16(const void* g, void* l) {
  __builtin_amdgcn_global_load_lds(
      (const __attribute__((address_space(1))) void*)g,
      (__attribute__((address_space(3))) void*)l, 16, 0, 0);
}

__device__ __forceinline__ unsigned pk2(float a, float b) {
  union { bf16 h[2]; unsigned u; } t;
  t.h[0] = (bf16)a; t.h[1] = (bf16)b;
  return t.u;
}

// XCD-chunked swizzle (nwg % 8 == 0): each XCD gets a contiguous work chunk.
__device__ __forceinline__ void xcd_map(int nx, int nwg, int& bx, int& by) {
  const int lin = blockIdx.y * nx + blockIdx.x;
  const int id = (lin & 7) * (nwg >> 3) + (lin >> 3);
  bx = id % nx;
  by = id / nx;
}

// ---------------- fused elementwise prep (rope+cast, one launch) ----------
__global__ __launch_bounds__(256) void prep_all(
    const float* __restrict__ x, bf16* __restrict__ xb, bf16* __restrict__ qr,
    const float* __restrict__ w0, const float* __restrict__ w1,
    const float* __restrict__ w2, bf16* __restrict__ o0,
    bf16* __restrict__ o1, bf16* __restrict__ o2) {
  const int bid = blockIdx.x;
  if (bid < 8192) {
    int idx = bid * 256 + threadIdx.x;
    int row = idx >> 9;
    int i = idx & 511;
    int h = i >> 5, d2 = i & 31;
    int pos = row & (SEQ - 1);
    int c0 = h * HD + d2;
    size_t base = (size_t)row * EMB;
    float x0 = x[base + c0], x1 = x[base + c0 + 32];
    float invf = exp2f(-(float)d2 * 0.4152410118609203f);
    float ang = (float)pos * invf;
    float sn, cs;
    sincosf(ang, &sn, &cs);
    qr[base + c0] = (bf16)(x0 * cs - x1 * sn);
    qr[base + c0 + 32] = (bf16)(x1 * cs + x0 * sn);
    xb[base + c0] = (bf16)x0;
    xb[base + c0 + 32] = (bf16)x1;
  } else {
    int i = ((bid - 8192) * 256 + threadIdx.x) * 4;
    const float* s; bf16* d; int off;
    if (i < 3 * 1024 * 1024) { s = w0; d = o0; off = i; }
    else if (i < 4 * 1024 * 1024) { s = w1; d = o1; off = i - 3 * 1024 * 1024; }
    else { s = w2; d = o2; off = i - 4 * 1024 * 1024; }
    float4 f = *(const float4*)(s + off);
    d[off] = (bf16)f.x; d[off + 1] = (bf16)f.y;
    d[off + 2] = (bf16)f.z; d[off + 3] = (bf16)f.w;
  }
}

// ---------------- fused in-proj GEMM: 256x128 tile, 4-deep pipeline -------
// Outputs: qb[token][1024] pre-scaled by 0.125; kv images per (b,h): 32 tiles
// of 64 keys {K 4096 | V 4096} in the attention LDS layout (K scaled log2e).
__global__ __launch_bounds__(512, 2) void gemm_in(
    const bf16* __restrict__ Aq, const bf16* __restrict__ Ax,
    const bf16* __restrict__ W, const float* __restrict__ bias,
    bf16* __restrict__ qb, bf16* __restrict__ kv) {
  __shared__ bf16 Ab[4][8192];   // 4 bufs x 256 rows x 32 cols
  __shared__ bf16 Bb[4][4096];   // 4 bufs x 128 rows x 32 cols
  const int tid = threadIdx.x, lane = tid & 63, wave = tid >> 6;
  const int quad = lane >> 4, l16 = lane & 15;
  const int wr = wave >> 1, wc = wave & 1;   // 4m x 2n wave grid
  int bx, by;
  xcd_map(24, 384, bx, by);
  const int m0 = by * 256, n0 = bx * 128;
  const bf16* A = (n0 < 2048) ? Aq : Ax;
  const int K = 1024;
  // staging: per tile 3 gll16/thread (A 2 passes of 128 rows, B 1 pass)
  const bf16* sa0 = A + (size_t)(m0 + (tid >> 2)) * K + (tid & 3) * 8;
  const bf16* sa1 = A + (size_t)(m0 + 128 + (tid >> 2)) * K + (tid & 3) * 8;
  const bf16* sw0 = W + (size_t)(n0 + (tid >> 2)) * K + (tid & 3) * 8;
  const int doff = tid * 8;
#pragma unroll
  for (int t = 0; t < 3; ++t) {          // prologue: tiles 0,1,2
    gll16(sa0 + t * 32, Ab[t] + doff);
    gll16(sa1 + t * 32, Ab[t] + 4096 + doff);
    gll16(sw0 + t * 32, Bb[t] + doff);
  }
  f32x4 acc[4][4] = {};
  for (int g = 0; g < 32; ++g) {
    if (g <= 29) asm volatile("s_waitcnt vmcnt(6)" ::: "memory");
    else         asm volatile("s_waitcnt vmcnt(0)" ::: "memory");
    __builtin_amdgcn_s_barrier();
    __builtin_amdgcn_sched_barrier(0);
    if (g + 3 < 32) {                    // stage tile g+3 into freed buffer
      const int k1 = (g + 3) * 32;
      bf16* da = Ab[(g + 3) & 3];
      bf16* db = Bb[(g + 3) & 3];
      gll16(sa0 + k1, da + doff);
      gll16(sa1 + k1, da + 4096 + doff);
      gll16(sw0 + k1, db + doff);
    }
    const bf16* As = Ab[g & 3];
    const bf16* Bs = Bb[g & 3];
    bf16x8 af[4], bw[4];
#pragma unroll
    for (int t = 0; t < 4; ++t) {
      af[t] = *(const bf16x8*)(As + (wr * 64 + t * 16 + l16) * 32 + quad * 8);
      bw[t] = *(const bf16x8*)(Bs + (wc * 64 + t * 16 + l16) * 32 + quad * 8);
    }
    __builtin_amdgcn_s_setprio(1);
#pragma unroll
    for (int mt = 0; mt < 4; ++mt)
#pragma unroll
      for (int nt = 0; nt < 4; ++nt)
        acc[mt][nt] = mfma16(af[mt], bw[nt], acc[mt][nt]);
    __builtin_amdgcn_s_setprio(0);
  }
  if (n0 < 1024) {
    // Q: scale 1/8 (exact in bf16)
#pragma unroll
    for (int mt = 0; mt < 4; ++mt)
      for (int nt = 0; nt < 4; ++nt) {
        const int n = n0 + wc * 64 + nt * 16 + l16;
        const float bv = bias[n];
#pragma unroll
        for (int r = 0; r < 4; ++r) {
          const int m = m0 + wr * 64 + mt * 16 + quad * 4 + r;
          qb[(size_t)m * 1024 + n] = (bf16)((acc[mt][nt][r] + bv) * 0.125f);
        }
      }
  } else if (n0 < 2048) {
    // K: scale log2(e), write into swizzled 64-key tile image
#pragma unroll
    for (int mt = 0; mt < 4; ++mt)
      for (int nt = 0; nt < 4; ++nt) {
        const int n = n0 + wc * 64 + nt * 16 + l16;
        const float bv = bias[n];
        const int kd = n - 1024, hh = kd >> 6, d = kd & 63;
        const int dc = d >> 3, dl = d & 7;
#pragma unroll
        for (int r = 0; r < 4; ++r) {
          const int m = m0 + wr * 64 + mt * 16 + quad * 4 + r;
          const int bb = m >> 11, s = m & 2047;
          const int tt = s >> 6, kr = s & 63;
          const size_t base = ((size_t)((bb * 16 + hh) * 32 + tt)) * 8192;
          kv[base + kr * 64 + ((dc ^ (kr & 7)) << 3) + dl] =
              (bf16)((acc[mt][nt][r] + bv) * 1.4426950408889634f);
        }
      }
  } else {
    // V: permuted+swizzled 64-key tile image, 4 tokens per bf16x4
#pragma unroll
    for (int mt = 0; mt < 4; ++mt)
      for (int nt = 0; nt < 4; ++nt) {
        const int n = n0 + wc * 64 + nt * 16 + l16;
        const float bv = bias[n];
        const int vd = n - 2048, hh = vd >> 6, d = vd & 63;
        const int m = m0 + wr * 64 + mt * 16 + quad * 4;
        const int bb = m >> 11, s = m & 2047;
        const int tt = s >> 6, kt = s & 63;
        const int g2 = kt >> 4, w = kt & 15;
        const int c = 2 * g2 + ((w >> 2) & 1);
        const int slot = (w & 8) ? 4 : 0;
        const size_t base = ((size_t)((bb * 16 + hh) * 32 + tt)) * 8192 + 4096;
        bf16x4 pkv;
#pragma unroll
        for (int r = 0; r < 4; ++r) pkv[r] = (bf16)(acc[mt][nt][r] + bv);
        *(bf16x4*)(kv + base + d * 64 + ((c ^ (d & 7)) << 3) + slot) = pkv;
      }
  }
}

// ---------------- GEMM 256x128, 4-deep pipeline: C = A @ W^T + bias -------
__global__ __launch_bounds__(512, 2) void gemm256(
    const bf16* __restrict__ A, const bf16* __restrict__ W,
    const float* __restrict__ bias,
    float* __restrict__ outF, bf16* __restrict__ outB,
    int M, int N, int K, int nbx) {
  __shared__ bf16 Ab[4][8192];
  __shared__ bf16 Bb[4][4096];
  const int tid = threadIdx.x, lane = tid & 63, wave = tid >> 6;
  const int quad = lane >> 4, l16 = lane & 15;
  const int wr = wave >> 1, wc = wave & 1;
  int bx, by;
  xcd_map(nbx, nbx * (M >> 8), bx, by);
  const int m0 = by * 256, n0 = bx * 128;
  const bf16* sa0 = A + (size_t)(m0 + (tid >> 2)) * K + (tid & 3) * 8;
  const bf16* sa1 = A + (size_t)(m0 + 128 + (tid >> 2)) * K + (tid & 3) * 8;
  const bf16* sw0 = W + (size_t)(n0 + (tid >> 2)) * K + (tid & 3) * 8;
  const int doff = tid * 8;
  const int nit = K >> 5;
#pragma unroll
  for (int t = 0; t < 3; ++t) {
    gll16(sa0 + t * 32, Ab[t] + doff);
    gll16(sa1 + t * 32, Ab[t] + 4096 + doff);
    gll16(sw0 + t * 32, Bb[t] + doff);
  }
  f32x4 acc[4][4] = {};
  for (int g = 0; g < nit; ++g) {
    if (g <= nit - 3) asm volatile("s_waitcnt vmcnt(6)" ::: "memory");
    else              asm volatile("s_waitcnt vmcnt(0)" ::: "memory");
    __builtin_amdgcn_s_barrier();
    __builtin_amdgcn_sched_barrier(0);
    if (g + 3 < nit) {
      const int k1 = (g + 3) * 32;
      bf16* da = Ab[(g + 3) & 3];
      bf16* db = Bb[(g + 3) & 3];
      gll16(sa0 + k1, da + doff);
      gll16(sa1 + k1, da + 4096 + doff);
      gll16(sw0 + k1, db + doff);
    }
    const bf16* As = Ab[g & 3];
    const bf16* Bs = Bb[g & 3];
    bf16x8 af[4], bw[4];
#pragma unroll
    for (int t = 0; t < 4; ++t) {
      af[t] = *(const bf16x8*)(As + (wr * 64 + t * 16 + l16) * 32 + quad * 8);
      bw[t] = *(const bf16x8*)(Bs + (wc * 64 + t * 16 + l16) * 32 + quad * 8);
    }
    __builtin_amdgcn_s_setprio(1);
#pragma unroll
    for (int mt = 0; mt < 4; ++mt)
#pragma unroll
      for (int nt = 0; nt < 4; ++nt)
        acc[mt][nt] = mfma16(af[mt], bw[nt], acc[mt][nt]);
    __builtin_amdgcn_s_setprio(0);
  }
#pragma unroll
  for (int mt = 0; mt < 4; ++mt)
    for (int nt = 0; nt < 4; ++nt) {
      const int n = n0 + wc * 64 + nt * 16 + l16;
      const float bv = bias ? bias[n] : 0.0f;
#pragma unroll
      for (int r = 0; r < 4; ++r) {
        const int m = m0 + wr * 64 + mt * 16 + quad * 4 + r;
        const float v = acc[mt][nt][r] + bv;
        if (outF) outF[(size_t)m * N + n] = v;
        if (outB) outB[(size_t)m * N + n] = (bf16)v;
      }
    }
}

// ---------------- GEMM 128x64 tiles (v15 dbuf, out-proj) ----------------
__global__ __launch_bounds__(256) void gemm_bt64(
    const bf16* __restrict__ A, const bf16* __restrict__ W,
    const float* __restrict__ bias, float* __restrict__ outF,
    int M, int N, int K) {
  __shared__ bf16 As[2][4096];
  __shared__ bf16 Bs[2][2048];
  const int tid = threadIdx.x, lane = tid & 63, wave = tid >> 6;
  const int quad = lane >> 4, l16 = lane & 15;
  int bx, by;
  xcd_map(16, 16 * 32, bx, by);
  const int m0 = by * 128, n0 = bx * 64;
  const int wm = (wave >> 1) * 64, wn = (wave & 1) * 32;
  const int srow = wave * 32 + (lane >> 2);
  const int srowB = wave * 16 + (lane >> 2);
  const int scol = (lane & 3) * 8;
  const bf16* a0 = A + (size_t)(m0 + srow) * K + scol;
  const bf16* a1 = A + (size_t)(m0 + srow + 16) * K + scol;
  const bf16* w0p = W + (size_t)(n0 + srowB) * K + scol;
  gll16(a0, As[0] + wave * 1024);
  gll16(a1, As[0] + wave * 1024 + 512);
  gll16(w0p, Bs[0] + wave * 512);
  f32x4 acc[4][2] = {};
  const int nit = K >> 5;
  for (int it = 0; it < nit; ++it) {
    const int cur = it & 1, nxt = cur ^ 1;
    if (it + 1 < nit) {
      const int k1 = (it + 1) * 32;
      gll16(a0 + k1, As[nxt] + wave * 1024);
      gll16(a1 + k1, As[nxt] + wave * 1024 + 512);
      gll16(w0p + k1, Bs[nxt] + wave * 512);
      asm volatile("s_waitcnt vmcnt(3)" ::: "memory");
    } else {
      asm volatile("s_waitcnt vmcnt(0)" ::: "memory");
    }
    __builtin_amdgcn_s_barrier();
    __builtin_amdgcn_sched_barrier(0);
    bf16x8 af[4], bw[2];
#pragma unroll
    for (int t = 0; t < 4; ++t)
      af[t] = *(const bf16x8*)(As[cur] + (wm + t * 16 + l16) * 32 + quad * 8);
#pragma unroll
    for (int t = 0; t < 2; ++t)
      bw[t] = *(const bf16x8*)(Bs[cur] + (wn + t * 16 + l16) * 32 + quad * 8);
#pragma unroll
    for (int mt = 0; mt < 4; ++mt)
#pragma unroll
      for (int nt = 0; nt < 2; ++nt)
        acc[mt][nt] = mfma16(af[mt], bw[nt], acc[mt][nt]);
    __builtin_amdgcn_sched_barrier(0);
    __builtin_amdgcn_s_barrier();
  }
#pragma unroll
  for (int mt = 0; mt < 4; ++mt)
    for (int nt = 0; nt < 2; ++nt) {
      const int n = n0 + wn + nt * 16 + l16;
      const float bv = bias[n];
#pragma unroll
      for (int r = 0; r < 4; ++r) {
        const int m = m0 + wm + mt * 16 + quad * 4 + r;
        outF[(size_t)m * N + n] = acc[mt][nt][r] + bv;
      }
    }
}

// ---------------- flash attention v14: dual-stream + counted vmcnt ---------
__global__ __launch_bounds__(256, 2) void attn14(
    const bf16* __restrict__ Q, const bf16* __restrict__ KV,
    bf16* __restrict__ ctx) {
  __shared__ __align__(16) bf16 kvb[2][16384];  // [buf][2 x (K 4096 | V 4096)]
  __shared__ float Linv[4][32];
  const int tid = threadIdx.x, lane = tid & 63, wave = tid >> 6;
  const int hi = lane >> 5, l31 = lane & 31, l7 = lane & 7;
  const int bid = blockIdx.x;
  const int hb = (bid & 7) * 4 + ((bid >> 3) & 3);
  const int qt = bid >> 5;              // 0..15
  const int h = hb & 15, b = hb >> 4;

  bf16x8 qf[4];
  {
    const int qrow = qt * 128 + wave * 32 + l31;
    const bf16* qp = Q + (size_t)(b * SEQ + qrow) * 1024 + h * HD + hi * 8;
#pragma unroll
    for (int t = 0; t < 4; ++t) qf[t] = *(const bf16x8*)(qp + t * 16);
  }
  asm volatile("s_waitcnt vmcnt(0)" ::: "memory");

  const int soff = tid * 8;
  const bf16* kvg = KV + ((size_t)(b * NH + h) * 32) * 8192 + soff;
#pragma unroll
  for (int i = 0; i < 8; ++i)
    gll16(kvg + i * 2048, kvb[0] + soff + i * 2048);
#pragma unroll
  for (int i = 0; i < 8; ++i)
    gll16(kvg + 16384 + i * 2048, kvb[1] + soff + i * 2048);

  f32x16 o0 = {}, o1 = {};
  float lpart = 0.0f;
  const f32x16 zf = {};

  for (int t = 0; t < 16; ++t) {
    if (t < 15) asm volatile("s_waitcnt vmcnt(8)" ::: "memory");
    else        asm volatile("s_waitcnt vmcnt(0)" ::: "memory");
    __builtin_amdgcn_s_barrier();
    __builtin_amdgcn_sched_barrier(0);
    const bf16* tb = kvb[t & 1];
#pragma unroll
    for (int half = 0; half < 2; ++half) {
      const bf16* ks = tb + half * 8192;
      const bf16* vs = ks + 4096;
      f32x16 s0, s1;
      __builtin_amdgcn_s_setprio(1);
      {
        const int swc = (hi ^ l7) * 8;
        bf16x8 k0 = *(const bf16x8*)(ks + l31 * 64 + swc);
        bf16x8 k1 = *(const bf16x8*)(ks + (32 + l31) * 64 + swc);
        s0 = mfma32(k0, qf[0], zf);
        s1 = mfma32(k1, qf[0], zf);
      }
#pragma unroll
      for (int tt = 1; tt < 4; ++tt) {
        const int swc = ((tt * 2 + hi) ^ l7) * 8;
        bf16x8 k0 = *(const bf16x8*)(ks + l31 * 64 + swc);
        bf16x8 k1 = *(const bf16x8*)(ks + (32 + l31) * 64 + swc);
        s0 = mfma32(k0, qf[tt], s0);
        s1 = mfma32(k1, qf[tt], s1);
      }
      __builtin_amdgcn_s_setprio(0);
      unsigned u[16];
#pragma unroll
      for (int g = 0; g < 8; ++g) {
        const int base = (g & 3) * 4;
        float e0, e1, e2, e3;
        if (g < 4) {
          e0 = __builtin_amdgcn_exp2f(s0[base]);
          e1 = __builtin_amdgcn_exp2f(s0[base + 1]);
          e2 = __builtin_amdgcn_exp2f(s0[base + 2]);
          e3 = __builtin_amdgcn_exp2f(s0[base + 3]);
        } else {
          e0 = __builtin_amdgcn_exp2f(s1[base]);
          e1 = __builtin_amdgcn_exp2f(s1[base + 1]);
          e2 = __builtin_amdgcn_exp2f(s1[base + 2]);
          e3 = __builtin_amdgcn_exp2f(s1[base + 3]);
        }
        lpart += (e0 + e1) + (e2 + e3);
        u[g * 2] = pk2(e0, e1);
        u[g * 2 + 1] = pk2(e2, e3);
      }
      __builtin_amdgcn_s_setprio(1);
#pragma unroll
      for (int kk = 0; kk < 4; ++kk) {
        union { unsigned w[4]; bf16x8 v; } fw;
        fw.w[0] = u[4 * kk]; fw.w[1] = u[4 * kk + 1];
        fw.w[2] = u[4 * kk + 2]; fw.w[3] = u[4 * kk + 3];
        const int c16 = (2 * kk + hi) ^ l7;
        bf16x8 v0 = *(const bf16x8*)(vs + l31 * 64 + c16 * 8);
        bf16x8 v1 = *(const bf16x8*)(vs + (32 + l31) * 64 + c16 * 8);
        o0 = mfma32(fw.v, v0, o0);
        o1 = mfma32(fw.v, v1, o1);
      }
      __builtin_amdgcn_s_setprio(0);
    }
    __builtin_amdgcn_sched_barrier(0);
    __builtin_amdgcn_s_barrier();
    __builtin_amdgcn_sched_barrier(0);
    if (t + 2 < 16) {
      const bf16* src = kvg + (size_t)(t + 2) * 16384;
      bf16* dst = kvb[t & 1] + soff;
#pragma unroll
      for (int i = 0; i < 8; ++i) gll16(src + i * 2048, dst + i * 2048);
    }
  }
  float ltot = lpart + __shfl_xor(lpart, 32, 64);
  if (lane < 32) Linv[wave][lane] = 1.0f / ltot;
#pragma unroll
  for (int r = 0; r < 16; ++r) {
    const int qloc = (r & 3) + 8 * (r >> 2) + 4 * hi;
    const float inv = Linv[wave][qloc];
    const int qrow = qt * 128 + wave * 32 + qloc;
    bf16* cp = ctx + (size_t)(b * SEQ + qrow) * EMB + h * HD;
    cp[l31] = (bf16)(o0[r] * inv);
    cp[32 + l31] = (bf16)(o1[r] * inv);
  }
}

// ---------------- residual + LayerNorm ----------------
__global__ __launch_bounds__(256) void ln1_k(
    const float* __restrict__ x, const float* __restrict__ ao,
    const float* __restrict__ g, const float* __restrict__ bta,
    float* __restrict__ hF, bf16* __restrict__ hB) {
  int row = blockIdx.x, tid = threadIdx.x;
  const float* xr = x + (size_t)row * EMB;
  const float* ar = ao + (size_t)row * EMB;
  float v[4], s = 0.0f, s2 = 0.0f;
#pragma unroll
  for (int i = 0; i < 4; ++i) {
    float t = xr[tid + i * 256] + ar[tid + i * 256];
    v[i] = t; s += t; s2 += t * t;
  }
#pragma unroll
  for (int off = 1; off < 64; off <<= 1) {
    s += __shfl_xor(s, off, 64);
    s2 += __shfl_xor(s2, off, 64);
  }
  __shared__ float red[8];
  int wave = tid >> 6, lane = tid & 63;
  if (lane == 0) { red[wave] = s; red[4 + wave] = s2; }
  __syncthreads();
  s = red[0] + red[1] + red[2] + red[3];
  s2 = red[4] + red[5] + red[6] + red[7];
  float mean = s * (1.0f / EMB);
  float var = s2 * (1.0f / EMB) - mean * mean;
  float inv = rsqrtf(var + 1e-5f);
#pragma unroll
  for (int i = 0; i < 4; ++i) {
    int c = tid + i * 256;
    float t = (v[i] - mean) * inv * g[c] + bta[c];
    hF[(size_t)row * EMB + c] = t;
    hB[(size_t)row * EMB + c] = (bf16)t;
  }
}

__global__ __launch_bounds__(256) void geglu_ln2(
    const float* __restrict__ h, const bf16* __restrict__ proj,
    const float* __restrict__ g, const float* __restrict__ bta,
    float* __restrict__ out) {
  int row = blockIdx.x, tid = threadIdx.x;
  const float* hr = h + (size_t)row * EMB;
  const bf16* pr = proj + (size_t)row * 2048;
  float v[4], s = 0.0f, s2 = 0.0f;
#pragma unroll
  for (int i = 0; i < 4; ++i) {
    int c = tid + i * 256;
    float val = (float)pr[c];
    float gate = (float)pr[1024 + c];
    float ge = 0.5f * gate * (1.0f + erff(gate * 0.70710678f));
    float t = hr[c] + val * ge;
    v[i] = t; s += t; s2 += t * t;
  }
#pragma unroll
  for (int off = 1; off < 64; off <<= 1) {
    s += __shfl_xor(s, off, 64);
    s2 += __shfl_xor(s2, off, 64);
  }
  __shared__ float red[8];
  int wave = tid >> 6, lane = tid & 63;
  if (lane == 0) { red[wave] = s; red[4 + wave] = s2; }
  __syncthreads();
  s = red[0] + red[1] + red[2] + red[3];
  s2 = red[4] + red[5] + red[6] + red[7];
  float mean = s * (1.0f / EMB);
  float var = s2 * (1.0f / EMB) - mean * mean;
  float inv = rsqrtf(var + 1e-5f);
#pragma unroll
  for (int i = 0; i < 4; ++i) {
    int c = tid + i * 256;
    out[(size_t)row * EMB + c] = (v[i] - mean) * inv * g[c] + bta[c];
  }
}

extern "C" void kernel_launch(void* const* d_in, const int* in_sizes, int n_in,
                              void* d_out, int out_size, void* d_ws, size_t ws_size,
                              hipStream_t stream) {
  const float* x = (const float*)d_in[0];
  const float* inW = (const float*)d_in[1];
  const float* inB = (const float*)d_in[2];
  const float* outW = (const float*)d_in[3];
  const float* opB = (const float*)d_in[4];
  const float* ggW = (const float*)d_in[5];
  const float* ggB = (const float*)d_in[6];
  const float* g1 = (const float*)d_in[7];
  const float* b1 = (const float*)d_in[8];
  const float* g2 = (const float*)d_in[9];
  const float* b2 = (const float*)d_in[10];
  float* out = (float*)d_out;
  char* ws = (char*)d_ws;
  const size_t MB = 1ull << 20;
  bf16* xb = (bf16*)(ws);              // 8 MB, dead after gemm_in
  bf16* hB = (bf16*)(ws);              // overlays xb (ln1 out)
  bf16* qr = (bf16*)(ws + 8 * MB);     // 8 MB, dead after gemm_in
  bf16* ctx = (bf16*)(ws + 8 * MB);    // overlays qr (attn output)
  bf16* wI = (bf16*)(ws + 16 * MB);    // 6 MB
  bf16* wO = (bf16*)(ws + 22 * MB);    // 2 MB
  bf16* wG = (bf16*)(ws + 24 * MB);    // 4 MB
  bf16* qb = (bf16*)(ws + 28 * MB);    // 8 MB, dead after attn
  bf16* kv = (bf16*)(ws + 36 * MB);    // 16 MB tile images, dead after attn
  bf16* projB = (bf16*)(ws + 28 * MB); // overlays qb+kv (GeGLU proj)
  float* ao = (float*)(ws + 52 * MB);  // 16 MB f32

  prep_all<<<8192 + 6144, 256, 0, stream>>>(x, xb, qr, inW, outW, ggW,
                                            wI, wO, wG);
  gemm_in<<<dim3(24, 16), 512, 0, stream>>>(qr, xb, wI, inB, qb, kv);
  attn14<<<512, 256, 0, stream>>>(qb, kv, ctx);
  gemm_bt64<<<dim3(16, 32), 256, 0, stream>>>(ctx, wO, opB, ao,
                                              NTOK, 1024, 1024);
  ln1_k<<<NTOK, 256, 0, stream>>>(x, ao, g1, b1, ao, hB);
  gemm256<<<dim3(16, 16), 512, 0, stream>>>(hB, wG, ggB, nullptr, projB,
                                            NTOK, 2048, 1024, 16);
  geglu_ln2<<<NTOK, 256, 0, stream>>>(ao, projB, g2, b2, out);
}

// Round 8
// 264.993 us; speedup vs baseline: 1.0511x; 1.0511x over previous
//
#include <hip/hip_runtime.h>

// TransformerBlock on MI355X (gfx950).
// v17: GEMM fix round. Keep v14's best-measured occupancy shape (128x128
// tiles, 256 threads, 3 blocks/CU) and attack the two measured problems:
// (a) the [128][32] fragment ds_read_b128 was an 8-way bank conflict (16
// lanes -> 2 four-bank groups); fixed with an intra-row XOR swizzle done at
// staging time (stage thread for row r reads global col-block c^(r&3); read
// uses quad^(l16&3)) -- gll16 dest stays linear, coalescing intact;
// (b) per-iter vmcnt(0) drain / double-barrier; replaced with a 3-buffer
// ring, ONE barrier per iter, counted vmcnt(4) (tile g+1 always in flight),
// staging AFTER the barrier into the buffer it just retired (WAR-safe).
// Applied to in-proj, GeGLU, out-proj. attn14/prep/LNs unchanged.

typedef __bf16 bf16;
typedef bf16 bf16x8 __attribute__((ext_vector_type(8)));
typedef bf16 bf16x4 __attribute__((ext_vector_type(4)));
typedef float f32x4 __attribute__((ext_vector_type(4)));
typedef float f32x16 __attribute__((ext_vector_type(16)));

#define EMB 1024
#define SEQ 2048
#define NTOK 4096
#define NH 16
#define HD 64

__device__ __forceinline__ f32x4 mfma16(bf16x8 a, bf16x8 b, f32x4 c) {
  return __builtin_amdgcn_mfma_f32_16x16x32_bf16(a, b, c, 0, 0, 0);
}
__device__ __forceinline__ f32x16 mfma32(bf16x8 a, bf16x8 b, f32x16 c) {
  return __builtin_amdgcn_mfma_f32_32x32x16_bf16(a, b, c, 0, 0, 0);
}

__device__ __forceinline__ void gll16(const void* g, void* l) {
  __builtin_amdgcn_global_load_lds(
      (const __attribute__((address_space(1))) void*)g,
      (__attribute__((address_space(3))) void*)l, 16, 0, 0);
}

__device__ __forceinline__ unsigned pk2(float a, float b) {
  union { bf16 h[2]; unsigned u; } t;
  t.h[0] = (bf16)a; t.h[1] = (bf16)b;
  return t.u;
}

// XCD-chunked swizzle (nwg % 8 == 0): each XCD gets a contiguous work chunk.
__device__ __forceinline__ void xcd_map(int nx, int nwg, int& bx, int& by) {
  const int lin = blockIdx.y * nx + blockIdx.x;
  const int id = (lin & 7) * (nwg >> 3) + (lin >> 3);
  bx = id % nx;
  by = id / nx;
}

// ---------------- fused elementwise prep (rope+cast, one launch) ----------
__global__ __launch_bounds__(256) void prep_all(
    const float* __restrict__ x, bf16* __restrict__ xb, bf16* __restrict__ qr,
    const float* __restrict__ w0, const float* __restrict__ w1,
    const float* __restrict__ w2, bf16* __restrict__ o0,
    bf16* __restrict__ o1, bf16* __restrict__ o2) {
  const int bid = blockIdx.x;
  if (bid < 8192) {
    int idx = bid * 256 + threadIdx.x;
    int row = idx >> 9;
    int i = idx & 511;
    int h = i >> 5, d2 = i & 31;
    int pos = row & (SEQ - 1);
    int c0 = h * HD + d2;
    size_t base = (size_t)row * EMB;
    float x0 = x[base + c0], x1 = x[base + c0 + 32];
    float invf = exp2f(-(float)d2 * 0.4152410118609203f);
    float ang = (float)pos * invf;
    float sn, cs;
    sincosf(ang, &sn, &cs);
    qr[base + c0] = (bf16)(x0 * cs - x1 * sn);
    qr[base + c0 + 32] = (bf16)(x1 * cs + x0 * sn);
    xb[base + c0] = (bf16)x0;
    xb[base + c0 + 32] = (bf16)x1;
  } else {
    int i = ((bid - 8192) * 256 + threadIdx.x) * 4;
    const float* s; bf16* d; int off;
    if (i < 3 * 1024 * 1024) { s = w0; d = o0; off = i; }
    else if (i < 4 * 1024 * 1024) { s = w1; d = o1; off = i - 3 * 1024 * 1024; }
    else { s = w2; d = o2; off = i - 4 * 1024 * 1024; }
    float4 f = *(const float4*)(s + off);
    d[off] = (bf16)f.x; d[off + 1] = (bf16)f.y;
    d[off + 2] = (bf16)f.z; d[off + 3] = (bf16)f.w;
  }
}

// ---------------- fused in-proj GEMM: ring3 + swizzle ----------------
// Outputs: qb[token][1024] pre-scaled by 0.125; kv images per (b,h): 32 tiles
// of 64 keys {K 4096 | V 4096} in the attention LDS layout (K scaled log2e).
__global__ __launch_bounds__(256) void gemm_in(
    const bf16* __restrict__ Aq, const bf16* __restrict__ Ax,
    const bf16* __restrict__ W, const float* __restrict__ bias,
    bf16* __restrict__ qb, bf16* __restrict__ kv) {
  __shared__ bf16 Ab[3][4096];
  __shared__ bf16 Bb[3][4096];
  const int tid = threadIdx.x, lane = tid & 63, wave = tid >> 6;
  const int quad = lane >> 4, l16 = lane & 15;
  int bx, by;
  xcd_map(24, 768, bx, by);
  const int m0 = by * 128, n0 = bx * 128;
  const bf16* A = (n0 < 2048) ? Aq : Ax;
  const int K = 1024;
  const int wm = (wave >> 1) * 64, wn = (wave & 1) * 64;
  const int srow = wave * 32 + (lane >> 2);
  // staging swizzle: row r's col-block c sources global col-block c^(r&3)
  const int scol = ((lane & 3) ^ ((lane >> 2) & 3)) * 8;
  const bf16* a0 = A + (size_t)(m0 + srow) * K + scol;
  const bf16* a1 = A + (size_t)(m0 + srow + 16) * K + scol;   // (r+16)&3 == r&3
  const bf16* w0p = W + (size_t)(n0 + srow) * K + scol;
  const bf16* w1p = W + (size_t)(n0 + srow + 16) * K + scol;
  const int sq = (quad ^ (l16 & 3)) * 8;    // fragment-read swizzled col
#pragma unroll
  for (int t = 0; t < 2; ++t) {             // prologue: tiles 0,1
    gll16(a0 + t * 32, Ab[t] + wave * 1024);
    gll16(a1 + t * 32, Ab[t] + wave * 1024 + 512);
    gll16(w0p + t * 32, Bb[t] + wave * 1024);
    gll16(w1p + t * 32, Bb[t] + wave * 1024 + 512);
  }
  f32x4 acc[4][4] = {};
  int rd = 0, wr = 2;
  for (int g = 0; g < 32; ++g) {
    if (g < 31) asm volatile("s_waitcnt vmcnt(4)" ::: "memory");
    else        asm volatile("s_waitcnt vmcnt(0)" ::: "memory");
    __builtin_amdgcn_s_barrier();           // also retires buf[wr] readers
    __builtin_amdgcn_sched_barrier(0);
    if (g + 2 < 32) {                       // stage tile g+2 (WAR-safe)
      const int k1 = (g + 2) * 32;
      bf16* da = Ab[wr];
      bf16* db = Bb[wr];
      gll16(a0 + k1, da + wave * 1024);
      gll16(a1 + k1, da + wave * 1024 + 512);
      gll16(w0p + k1, db + wave * 1024);
      gll16(w1p + k1, db + wave * 1024 + 512);
    }
    const bf16* As = Ab[rd];
    const bf16* Bs = Bb[rd];
    bf16x8 af[4], bw[4];
#pragma unroll
    for (int t = 0; t < 4; ++t) {
      af[t] = *(const bf16x8*)(As + (wm + t * 16 + l16) * 32 + sq);
      bw[t] = *(const bf16x8*)(Bs + (wn + t * 16 + l16) * 32 + sq);
    }
    __builtin_amdgcn_s_setprio(1);
#pragma unroll
    for (int mt = 0; mt < 4; ++mt)
#pragma unroll
      for (int nt = 0; nt < 4; ++nt)
        acc[mt][nt] = mfma16(af[mt], bw[nt], acc[mt][nt]);
    __builtin_amdgcn_s_setprio(0);
    rd = (rd + 1 == 3) ? 0 : rd + 1;
    wr = (wr + 1 == 3) ? 0 : wr + 1;
  }
  if (n0 < 1024) {
    // Q: scale 1/8 (exact in bf16)
#pragma unroll
    for (int mt = 0; mt < 4; ++mt)
      for (int nt = 0; nt < 4; ++nt) {
        const int n = n0 + wn + nt * 16 + l16;
        const float bv = bias[n];
#pragma unroll
        for (int r = 0; r < 4; ++r) {
          const int m = m0 + wm + mt * 16 + quad * 4 + r;
          qb[(size_t)m * 1024 + n] = (bf16)((acc[mt][nt][r] + bv) * 0.125f);
        }
      }
  } else if (n0 < 2048) {
    // K: scale log2(e), write into swizzled 64-key tile image
#pragma unroll
    for (int mt = 0; mt < 4; ++mt)
      for (int nt = 0; nt < 4; ++nt) {
        const int n = n0 + wn + nt * 16 + l16;
        const float bv = bias[n];
        const int kd = n - 1024, hh = kd >> 6, d = kd & 63;
        const int dc = d >> 3, dl = d & 7;
#pragma unroll
        for (int r = 0; r < 4; ++r) {
          const int m = m0 + wm + mt * 16 + quad * 4 + r;
          const int bb = m >> 11, s = m & 2047;
          const int t = s >> 6, kr = s & 63;
          const size_t base = ((size_t)((bb * 16 + hh) * 32 + t)) * 8192;
          kv[base + kr * 64 + ((dc ^ (kr & 7)) << 3) + dl] =
              (bf16)((acc[mt][nt][r] + bv) * 1.4426950408889634f);
        }
      }
  } else {
    // V: permuted+swizzled 64-key tile image, 4 tokens per bf16x4
#pragma unroll
    for (int mt = 0; mt < 4; ++mt)
      for (int nt = 0; nt < 4; ++nt) {
        const int n = n0 + wn + nt * 16 + l16;
        const float bv = bias[n];
        const int vd = n - 2048, hh = vd >> 6, d = vd & 63;
        const int m = m0 + wm + mt * 16 + quad * 4;
        const int bb = m >> 11, s = m & 2047;
        const int t = s >> 6, kt = s & 63;
        const int g2 = kt >> 4, w = kt & 15;
        const int c = 2 * g2 + ((w >> 2) & 1);
        const int slot = (w & 8) ? 4 : 0;
        const size_t base = ((size_t)((bb * 16 + hh) * 32 + t)) * 8192 + 4096;
        bf16x4 pkv;
#pragma unroll
        for (int r = 0; r < 4; ++r) pkv[r] = (bf16)(acc[mt][nt][r] + bv);
        *(bf16x4*)(kv + base + d * 64 + ((c ^ (d & 7)) << 3) + slot) = pkv;
      }
  }
}

// ---------------- GEMM 128x128 ring3+swz: C = A @ W^T + bias --------------
__global__ __launch_bounds__(256) void gemm_bt(
    const bf16* __restrict__ A, const bf16* __restrict__ W,
    const float* __restrict__ bias,
    float* __restrict__ outF, bf16* __restrict__ outB,
    int M, int N, int K, int nbx) {
  __shared__ bf16 Ab[3][4096];
  __shared__ bf16 Bb[3][4096];
  const int tid = threadIdx.x, lane = tid & 63, wave = tid >> 6;
  const int quad = lane >> 4, l16 = lane & 15;
  int bx, by;
  xcd_map(nbx, nbx * (M >> 7), bx, by);
  const int m0 = by * 128, n0 = bx * 128;
  const int wm = (wave >> 1) * 64, wn = (wave & 1) * 64;
  const int srow = wave * 32 + (lane >> 2);
  const int scol = ((lane & 3) ^ ((lane >> 2) & 3)) * 8;
  const bf16* a0 = A + (size_t)(m0 + srow) * K + scol;
  const bf16* a1 = A + (size_t)(m0 + srow + 16) * K + scol;
  const bf16* w0p = W + (size_t)(n0 + srow) * K + scol;
  const bf16* w1p = W + (size_t)(n0 + srow + 16) * K + scol;
  const int sq = (quad ^ (l16 & 3)) * 8;
  const int nit = K >> 5;
#pragma unroll
  for (int t = 0; t < 2; ++t) {
    gll16(a0 + t * 32, Ab[t] + wave * 1024);
    gll16(a1 + t * 32, Ab[t] + wave * 1024 + 512);
    gll16(w0p + t * 32, Bb[t] + wave * 1024);
    gll16(w1p + t * 32, Bb[t] + wave * 1024 + 512);
  }
  f32x4 acc[4][4] = {};
  int rd = 0, wr = 2;
  for (int g = 0; g < nit; ++g) {
    if (g < nit - 1) asm volatile("s_waitcnt vmcnt(4)" ::: "memory");
    else             asm volatile("s_waitcnt vmcnt(0)" ::: "memory");
    __builtin_amdgcn_s_barrier();
    __builtin_amdgcn_sched_barrier(0);
    if (g + 2 < nit) {
      const int k1 = (g + 2) * 32;
      bf16* da = Ab[wr];
      bf16* db = Bb[wr];
      gll16(a0 + k1, da + wave * 1024);
      gll16(a1 + k1, da + wave * 1024 + 512);
      gll16(w0p + k1, db + wave * 1024);
      gll16(w1p + k1, db + wave * 1024 + 512);
    }
    const bf16* As = Ab[rd];
    const bf16* Bs = Bb[rd];
    bf16x8 af[4], bw[4];
#pragma unroll
    for (int t = 0; t < 4; ++t) {
      af[t] = *(const bf16x8*)(As + (wm + t * 16 + l16) * 32 + sq);
      bw[t] = *(const bf16x8*)(Bs + (wn + t * 16 + l16) * 32 + sq);
    }
    __builtin_amdgcn_s_setprio(1);
#pragma unroll
    for (int mt = 0; mt < 4; ++mt)
#pragma unroll
      for (int nt = 0; nt < 4; ++nt)
        acc[mt][nt] = mfma16(af[mt], bw[nt], acc[mt][nt]);
    __builtin_amdgcn_s_setprio(0);
    rd = (rd + 1 == 3) ? 0 : rd + 1;
    wr = (wr + 1 == 3) ? 0 : wr + 1;
  }
#pragma unroll
  for (int mt = 0; mt < 4; ++mt)
    for (int nt = 0; nt < 4; ++nt) {
      const int n = n0 + wn + nt * 16 + l16;
      const float bv = bias ? bias[n] : 0.0f;
#pragma unroll
      for (int r = 0; r < 4; ++r) {
        const int m = m0 + wm + mt * 16 + quad * 4 + r;
        const float v = acc[mt][nt][r] + bv;
        if (outF) outF[(size_t)m * N + n] = v;
        if (outB) outB[(size_t)m * N + n] = (bf16)v;
      }
    }
}

// ---------------- GEMM 128x64 ring3+swz (out-proj) ----------------
__global__ __launch_bounds__(256) void gemm_bt64(
    const bf16* __restrict__ A, const bf16* __restrict__ W,
    const float* __restrict__ bias, float* __restrict__ outF,
    int M, int N, int K) {
  __shared__ bf16 Ab[3][4096];
  __shared__ bf16 Bb[3][2048];
  const int tid = threadIdx.x, lane = tid & 63, wave = tid >> 6;
  const int quad = lane >> 4, l16 = lane & 15;
  int bx, by;
  xcd_map(16, 16 * 32, bx, by);
  const int m0 = by * 128, n0 = bx * 64;
  const int wm = (wave >> 1) * 64, wn = (wave & 1) * 32;
  const int srow = wave * 32 + (lane >> 2);
  const int srowB = wave * 16 + (lane >> 2);
  const int scol = ((lane & 3) ^ ((lane >> 2) & 3)) * 8;
  const bf16* a0 = A + (size_t)(m0 + srow) * K + scol;
  const bf16* a1 = A + (size_t)(m0 + srow + 16) * K + scol;
  const bf16* w0p = W + (size_t)(n0 + srowB) * K + scol;
  const int sq = (quad ^ (l16 & 3)) * 8;
  const int nit = K >> 5;
#pragma unroll
  for (int t = 0; t < 2; ++t) {
    gll16(a0 + t * 32, Ab[t] + wave * 1024);
    gll16(a1 + t * 32, Ab[t] + wave * 1024 + 512);
    gll16(w0p + t * 32, Bb[t] + wave * 512);
  }
  f32x4 acc[4][2] = {};
  int rd = 0, wr = 2;
  for (int g = 0; g < nit; ++g) {
    if (g < nit - 1) asm volatile("s_waitcnt vmcnt(3)" ::: "memory");
    else             asm volatile("s_waitcnt vmcnt(0)" ::: "memory");
    __builtin_amdgcn_s_barrier();
    __builtin_amdgcn_sched_barrier(0);
    if (g + 2 < nit) {
      const int k1 = (g + 2) * 32;
      gll16(a0 + k1, Ab[wr] + wave * 1024);
      gll16(a1 + k1, Ab[wr] + wave * 1024 + 512);
      gll16(w0p + k1, Bb[wr] + wave * 512);
    }
    const bf16* As = Ab[rd];
    const bf16* Bs = Bb[rd];
    bf16x8 af[4], bw[2];
#pragma unroll
    for (int t = 0; t < 4; ++t)
      af[t] = *(const bf16x8*)(As + (wm + t * 16 + l16) * 32 + sq);
#pragma unroll
    for (int t = 0; t < 2; ++t)
      bw[t] = *(const bf16x8*)(Bs + (wn + t * 16 + l16) * 32 + sq);
    __builtin_amdgcn_s_setprio(1);
#pragma unroll
    for (int mt = 0; mt < 4; ++mt)
#pragma unroll
      for (int nt = 0; nt < 2; ++nt)
        acc[mt][nt] = mfma16(af[mt], bw[nt], acc[mt][nt]);
    __builtin_amdgcn_s_setprio(0);
    rd = (rd + 1 == 3) ? 0 : rd + 1;
    wr = (wr + 1 == 3) ? 0 : wr + 1;
  }
#pragma unroll
  for (int mt = 0; mt < 4; ++mt)
    for (int nt = 0; nt < 2; ++nt) {
      const int n = n0 + wn + nt * 16 + l16;
      const float bv = bias[n];
#pragma unroll
      for (int r = 0; r < 4; ++r) {
        const int m = m0 + wm + mt * 16 + quad * 4 + r;
        outF[(size_t)m * N + n] = acc[mt][nt][r] + bv;
      }
    }
}

// ---------------- flash attention v14: dual-stream + counted vmcnt ---------
__global__ __launch_bounds__(256, 2) void attn14(
    const bf16* __restrict__ Q, const bf16* __restrict__ KV,
    bf16* __restrict__ ctx) {
  __shared__ __align__(16) bf16 kvb[2][16384];  // [buf][2 x (K 4096 | V 4096)]
  __shared__ float Linv[4][32];
  const int tid = threadIdx.x, lane = tid & 63, wave = tid >> 6;
  const int hi = lane >> 5, l31 = lane & 31, l7 = lane & 7;
  const int bid = blockIdx.x;
  const int hb = (bid & 7) * 4 + ((bid >> 3) & 3);
  const int qt = bid >> 5;              // 0..15
  const int h = hb & 15, b = hb >> 4;

  bf16x8 qf[4];
  {
    const int qrow = qt * 128 + wave * 32 + l31;
    const bf16* qp = Q + (size_t)(b * SEQ + qrow) * 1024 + h * HD + hi * 8;
#pragma unroll
    for (int t = 0; t < 4; ++t) qf[t] = *(const bf16x8*)(qp + t * 16);
  }
  asm volatile("s_waitcnt vmcnt(0)" ::: "memory");

  const int soff = tid * 8;
  const bf16* kvg = KV + ((size_t)(b * NH + h) * 32) * 8192 + soff;
#pragma unroll
  for (int i = 0; i < 8; ++i)
    gll16(kvg + i * 2048, kvb[0] + soff + i * 2048);
#pragma unroll
  for (int i = 0; i < 8; ++i)
    gll16(kvg + 16384 + i * 2048, kvb[1] + soff + i * 2048);

  f32x16 o0 = {}, o1 = {};
  float lpart = 0.0f;
  const f32x16 zf = {};

  for (int t = 0; t < 16; ++t) {
    if (t < 15) asm volatile("s_waitcnt vmcnt(8)" ::: "memory");
    else        asm volatile("s_waitcnt vmcnt(0)" ::: "memory");
    __builtin_amdgcn_s_barrier();
    __builtin_amdgcn_sched_barrier(0);
    const bf16* tb = kvb[t & 1];
#pragma unroll
    for (int half = 0; half < 2; ++half) {
      const bf16* ks = tb + half * 8192;
      const bf16* vs = ks + 4096;
      f32x16 s0, s1;
      __builtin_amdgcn_s_setprio(1);
      {
        const int swc = (hi ^ l7) * 8;
        bf16x8 k0 = *(const bf16x8*)(ks + l31 * 64 + swc);
        bf16x8 k1 = *(const bf16x8*)(ks + (32 + l31) * 64 + swc);
        s0 = mfma32(k0, qf[0], zf);
        s1 = mfma32(k1, qf[0], zf);
      }
#pragma unroll
      for (int tt = 1; tt < 4; ++tt) {
        const int swc = ((tt * 2 + hi) ^ l7) * 8;
        bf16x8 k0 = *(const bf16x8*)(ks + l31 * 64 + swc);
        bf16x8 k1 = *(const bf16x8*)(ks + (32 + l31) * 64 + swc);
        s0 = mfma32(k0, qf[tt], s0);
        s1 = mfma32(k1, qf[tt], s1);
      }
      __builtin_amdgcn_s_setprio(0);
      unsigned u[16];
#pragma unroll
      for (int g = 0; g < 8; ++g) {
        const int base = (g & 3) * 4;
        float e0, e1, e2, e3;
        if (g < 4) {
          e0 = __builtin_amdgcn_exp2f(s0[base]);
          e1 = __builtin_amdgcn_exp2f(s0[base + 1]);
          e2 = __builtin_amdgcn_exp2f(s0[base + 2]);
          e3 = __builtin_amdgcn_exp2f(s0[base + 3]);
        } else {
          e0 = __builtin_amdgcn_exp2f(s1[base]);
          e1 = __builtin_amdgcn_exp2f(s1[base + 1]);
          e2 = __builtin_amdgcn_exp2f(s1[base + 2]);
          e3 = __builtin_amdgcn_exp2f(s1[base + 3]);
        }
        lpart += (e0 + e1) + (e2 + e3);
        u[g * 2] = pk2(e0, e1);
        u[g * 2 + 1] = pk2(e2, e3);
      }
      __builtin_amdgcn_s_setprio(1);
#pragma unroll
      for (int kk = 0; kk < 4; ++kk) {
        union { unsigned w[4]; bf16x8 v; } fw;
        fw.w[0] = u[4 * kk]; fw.w[1] = u[4 * kk + 1];
        fw.w[2] = u[4 * kk + 2]; fw.w[3] = u[4 * kk + 3];
        const int c16 = (2 * kk + hi) ^ l7;
        bf16x8 v0 = *(const bf16x8*)(vs + l31 * 64 + c16 * 8);
        bf16x8 v1 = *(const bf16x8*)(vs + (32 + l31) * 64 + c16 * 8);
        o0 = mfma32(fw.v, v0, o0);
        o1 = mfma32(fw.v, v1, o1);
      }
      __builtin_amdgcn_s_setprio(0);
    }
    __builtin_amdgcn_sched_barrier(0);
    __builtin_amdgcn_s_barrier();
    __builtin_amdgcn_sched_barrier(0);
    if (t + 2 < 16) {
      const bf16* src = kvg + (size_t)(t + 2) * 16384;
      bf16* dst = kvb[t & 1] + soff;
#pragma unroll
      for (int i = 0; i < 8; ++i) gll16(src + i * 2048, dst + i * 2048);
    }
  }
  float ltot = lpart + __shfl_xor(lpart, 32, 64);
  if (lane < 32) Linv[wave][lane] = 1.0f / ltot;
#pragma unroll
  for (int r = 0; r < 16; ++r) {
    const int qloc = (r & 3) + 8 * (r >> 2) + 4 * hi;
    const float inv = Linv[wave][qloc];
    const int qrow = qt * 128 + wave * 32 + qloc;
    bf16* cp = ctx + (size_t)(b * SEQ + qrow) * EMB + h * HD;
    cp[l31] = (bf16)(o0[r] * inv);
    cp[32 + l31] = (bf16)(o1[r] * inv);
  }
}

// ---------------- residual + LayerNorm ----------------
__global__ __launch_bounds__(256) void ln1_k(
    const float* __restrict__ x, const float* __restrict__ ao,
    const float* __restrict__ g, const float* __restrict__ bta,
    float* __restrict__ hF, bf16* __restrict__ hB) {
  int row = blockIdx.x, tid = threadIdx.x;
  const float* xr = x + (size_t)row * EMB;
  const float* ar = ao + (size_t)row * EMB;
  float v[4], s = 0.0f, s2 = 0.0f;
#pragma unroll
  for (int i = 0; i < 4; ++i) {
    float t = xr[tid + i * 256] + ar[tid + i * 256];
    v[i] = t; s += t; s2 += t * t;
  }
#pragma unroll
  for (int off = 1; off < 64; off <<= 1) {
    s += __shfl_xor(s, off, 64);
    s2 += __shfl_xor(s2, off, 64);
  }
  __shared__ float red[8];
  int wave = tid >> 6, lane = tid & 63;
  if (lane == 0) { red[wave] = s; red[4 + wave] = s2; }
  __syncthreads();
  s = red[0] + red[1] + red[2] + red[3];
  s2 = red[4] + red[5] + red[6] + red[7];
  float mean = s * (1.0f / EMB);
  float var = s2 * (1.0f / EMB) - mean * mean;
  float inv = rsqrtf(var + 1e-5f);
#pragma unroll
  for (int i = 0; i < 4; ++i) {
    int c = tid + i * 256;
    float t = (v[i] - mean) * inv * g[c] + bta[c];
    hF[(size_t)row * EMB + c] = t;
    hB[(size_t)row * EMB + c] = (bf16)t;
  }
}

__global__ __launch_bounds__(256) void geglu_ln2(
    const float* __restrict__ h, const bf16* __restrict__ proj,
    const float* __restrict__ g, const float* __restrict__ bta,
    float* __restrict__ out) {
  int row = blockIdx.x, tid = threadIdx.x;
  const float* hr = h + (size_t)row * EMB;
  const bf16* pr = proj + (size_t)row * 2048;
  float v[4], s = 0.0f, s2 = 0.0f;
#pragma unroll
  for (int i = 0; i < 4; ++i) {
    int c = tid + i * 256;
    float val = (float)pr[c];
    float gate = (float)pr[1024 + c];
    float ge = 0.5f * gate * (1.0f + erff(gate * 0.70710678f));
    float t = hr[c] + val * ge;
    v[i] = t; s += t; s2 += t * t;
  }
#pragma unroll
  for (int off = 1; off < 64; off <<= 1) {
    s += __shfl_xor(s, off, 64);
    s2 += __shfl_xor(s2, off, 64);
  }
  __shared__ float red[8];
  int wave = tid >> 6, lane = tid & 63;
  if (lane == 0) { red[wave] = s; red[4 + wave] = s2; }
  __syncthreads();
  s = red[0] + red[1] + red[2] + red[3];
  s2 = red[4] + red[5] + red[6] + red[7];
  float mean = s * (1.0f / EMB);
  float var = s2 * (1.0f / EMB) - mean * mean;
  float inv = rsqrtf(var + 1e-5f);
#pragma unroll
  for (int i = 0; i < 4; ++i) {
    int c = tid + i * 256;
    out[(size_t)row * EMB + c] = (v[i] - mean) * inv * g[c] + bta[c];
  }
}

extern "C" void kernel_launch(void* const* d_in, const int* in_sizes, int n_in,
                              void* d_out, int out_size, void* d_ws, size_t ws_size,
                              hipStream_t stream) {
  const float* x = (const float*)d_in[0];
  const float* inW = (const float*)d_in[1];
  const float* inB = (const float*)d_in[2];
  const float* outW = (const float*)d_in[3];
  const float* opB = (const float*)d_in[4];
  const float* ggW = (const float*)d_in[5];
  const float* ggB = (const float*)d_in[6];
  const float* g1 = (const float*)d_in[7];
  const float* b1 = (const float*)d_in[8];
  const float* g2 = (const float*)d_in[9];
  const float* b2 = (const float*)d_in[10];
  float* out = (float*)d_out;
  char* ws = (char*)d_ws;
  const size_t MB = 1ull << 20;
  bf16* xb = (bf16*)(ws);              // 8 MB, dead after gemm_in
  bf16* hB = (bf16*)(ws);              // overlays xb (ln1 out)
  bf16* qr = (bf16*)(ws + 8 * MB);     // 8 MB, dead after gemm_in
  bf16* ctx = (bf16*)(ws + 8 * MB);    // overlays qr (attn output)
  bf16* wI = (bf16*)(ws + 16 * MB);    // 6 MB
  bf16* wO = (bf16*)(ws + 22 * MB);    // 2 MB
  bf16* wG = (bf16*)(ws + 24 * MB);    // 4 MB
  bf16* qb = (bf16*)(ws + 28 * MB);    // 8 MB, dead after attn
  bf16* kv = (bf16*)(ws + 36 * MB);    // 16 MB tile images, dead after attn
  bf16* projB = (bf16*)(ws + 28 * MB); // overlays qb+kv (GeGLU proj)
  float* ao = (float*)(ws + 52 * MB);  // 16 MB f32

  prep_all<<<8192 + 6144, 256, 0, stream>>>(x, xb, qr, inW, outW, ggW,
                                            wI, wO, wG);
  gemm_in<<<dim3(24, 32), 256, 0, stream>>>(qr, xb, wI, inB, qb, kv);
  attn14<<<512, 256, 0, stream>>>(qb, kv, ctx);
  gemm_bt64<<<dim3(16, 32), 256, 0, stream>>>(ctx, wO, opB, ao,
                                              NTOK, 1024, 1024);
  ln1_k<<<NTOK, 256, 0, stream>>>(x, ao, g1, b1, ao, hB);
  gemm_bt<<<dim3(16, 32), 256, 0, stream>>>(hB, wG, ggB, nullptr, projB,
                                            NTOK, 2048, 1024, 16);
  geglu_ln2<<<NTOK, 256, 0, stream>>>(ao, projB, g2, b2, out);
}

// Round 9
// 263.799 us; speedup vs baseline: 1.0559x; 1.0045x over previous
//
#include <hip/hip_runtime.h>

// TransformerBlock on MI355X (gfx950).
// v18: gemm_in REVERTED to its measured-best variant (v14: single-buffered
// __syncthreads loop, 16KB LDS, plain grid order, 54.0us). Four successive
// hand-scheduled restructures (dbuf/ring/swizzle, v15-v17) all regressed it
// (60/63/68us) despite lowering FETCH -- the kernel is latency- not
// fetch-bound and compiler scheduling beats the pinned schedules (m141).
// GeGLU (gemm_bt ring3+swz), out-proj (gemm_bt64 ring3+swz), attn14,
// prep_all, LNs unchanged from v17.

typedef __bf16 bf16;
typedef bf16 bf16x8 __attribute__((ext_vector_type(8)));
typedef bf16 bf16x4 __attribute__((ext_vector_type(4)));
typedef float f32x4 __attribute__((ext_vector_type(4)));
typedef float f32x16 __attribute__((ext_vector_type(16)));

#define EMB 1024
#define SEQ 2048
#define NTOK 4096
#define NH 16
#define HD 64

__device__ __forceinline__ f32x4 mfma16(bf16x8 a, bf16x8 b, f32x4 c) {
  return __builtin_amdgcn_mfma_f32_16x16x32_bf16(a, b, c, 0, 0, 0);
}
__device__ __forceinline__ f32x16 mfma32(bf16x8 a, bf16x8 b, f32x16 c) {
  return __builtin_amdgcn_mfma_f32_32x32x16_bf16(a, b, c, 0, 0, 0);
}

__device__ __forceinline__ void gll16(const void* g, void* l) {
  __builtin_amdgcn_global_load_lds(
      (const __attribute__((address_space(1))) void*)g,
      (__attribute__((address_space(3))) void*)l, 16, 0, 0);
}

__device__ __forceinline__ unsigned pk2(float a, float b) {
  union { bf16 h[2]; unsigned u; } t;
  t.h[0] = (bf16)a; t.h[1] = (bf16)b;
  return t.u;
}

// XCD-chunked swizzle (nwg % 8 == 0): each XCD gets a contiguous work chunk.
__device__ __forceinline__ void xcd_map(int nx, int nwg, int& bx, int& by) {
  const int lin = blockIdx.y * nx + blockIdx.x;
  const int id = (lin & 7) * (nwg >> 3) + (lin >> 3);
  bx = id % nx;
  by = id / nx;
}

// ---------------- fused elementwise prep (rope+cast, one launch) ----------
__global__ __launch_bounds__(256) void prep_all(
    const float* __restrict__ x, bf16* __restrict__ xb, bf16* __restrict__ qr,
    const float* __restrict__ w0, const float* __restrict__ w1,
    const float* __restrict__ w2, bf16* __restrict__ o0,
    bf16* __restrict__ o1, bf16* __restrict__ o2) {
  const int bid = blockIdx.x;
  if (bid < 8192) {
    int idx = bid * 256 + threadIdx.x;
    int row = idx >> 9;
    int i = idx & 511;
    int h = i >> 5, d2 = i & 31;
    int pos = row & (SEQ - 1);
    int c0 = h * HD + d2;
    size_t base = (size_t)row * EMB;
    float x0 = x[base + c0], x1 = x[base + c0 + 32];
    float invf = exp2f(-(float)d2 * 0.4152410118609203f);
    float ang = (float)pos * invf;
    float sn, cs;
    sincosf(ang, &sn, &cs);
    qr[base + c0] = (bf16)(x0 * cs - x1 * sn);
    qr[base + c0 + 32] = (bf16)(x1 * cs + x0 * sn);
    xb[base + c0] = (bf16)x0;
    xb[base + c0 + 32] = (bf16)x1;
  } else {
    int i = ((bid - 8192) * 256 + threadIdx.x) * 4;
    const float* s; bf16* d; int off;
    if (i < 3 * 1024 * 1024) { s = w0; d = o0; off = i; }
    else if (i < 4 * 1024 * 1024) { s = w1; d = o1; off = i - 3 * 1024 * 1024; }
    else { s = w2; d = o2; off = i - 4 * 1024 * 1024; }
    float4 f = *(const float4*)(s + off);
    d[off] = (bf16)f.x; d[off + 1] = (bf16)f.y;
    d[off + 2] = (bf16)f.z; d[off + 3] = (bf16)f.w;
  }
}

// ---------------- fused in-proj GEMM (v14 measured-best structure) --------
// Outputs: qb[token][1024] pre-scaled by 0.125; kv images per (b,h): 32 tiles
// of 64 keys {K 4096 | V 4096} in the attention LDS layout (K scaled log2e).
__global__ __launch_bounds__(256) void gemm_in(
    const bf16* __restrict__ Aq, const bf16* __restrict__ Ax,
    const bf16* __restrict__ W, const float* __restrict__ bias,
    bf16* __restrict__ qb, bf16* __restrict__ kv) {
  __shared__ bf16 As[128 * 32];
  __shared__ bf16 Bs[128 * 32];
  const int tid = threadIdx.x, lane = tid & 63, wave = tid >> 6;
  const int quad = lane >> 4, l16 = lane & 15;
  const int m0 = blockIdx.y * 128, n0 = blockIdx.x * 128;
  const bf16* A = (n0 < 2048) ? Aq : Ax;
  const int K = 1024;
  const int wm = (wave >> 1) * 64, wn = (wave & 1) * 64;
  const int srow = wave * 32 + (lane >> 2);
  const int scol = (lane & 3) * 8;
  f32x4 acc[4][4] = {};
  for (int k0 = 0; k0 < K; k0 += 32) {
    __syncthreads();
    gll16(A + (size_t)(m0 + srow) * K + k0 + scol, As + wave * 1024);
    gll16(A + (size_t)(m0 + srow + 16) * K + k0 + scol, As + wave * 1024 + 512);
    gll16(W + (size_t)(n0 + srow) * K + k0 + scol, Bs + wave * 1024);
    gll16(W + (size_t)(n0 + srow + 16) * K + k0 + scol, Bs + wave * 1024 + 512);
    __syncthreads();
    bf16x8 af[4], bw[4];
#pragma unroll
    for (int t = 0; t < 4; ++t) {
      af[t] = *(const bf16x8*)(As + (wm + t * 16 + l16) * 32 + quad * 8);
      bw[t] = *(const bf16x8*)(Bs + (wn + t * 16 + l16) * 32 + quad * 8);
    }
#pragma unroll
    for (int mt = 0; mt < 4; ++mt)
#pragma unroll
      for (int nt = 0; nt < 4; ++nt)
        acc[mt][nt] = mfma16(af[mt], bw[nt], acc[mt][nt]);
  }
  if (n0 < 1024) {
    // Q: scale 1/8 (exact in bf16)
#pragma unroll
    for (int mt = 0; mt < 4; ++mt)
      for (int nt = 0; nt < 4; ++nt) {
        const int n = n0 + wn + nt * 16 + l16;
        const float bv = bias[n];
#pragma unroll
        for (int r = 0; r < 4; ++r) {
          const int m = m0 + wm + mt * 16 + quad * 4 + r;
          qb[(size_t)m * 1024 + n] = (bf16)((acc[mt][nt][r] + bv) * 0.125f);
        }
      }
  } else if (n0 < 2048) {
    // K: scale log2(e), write into swizzled 64-key tile image
#pragma unroll
    for (int mt = 0; mt < 4; ++mt)
      for (int nt = 0; nt < 4; ++nt) {
        const int n = n0 + wn + nt * 16 + l16;
        const float bv = bias[n];
        const int kd = n - 1024, hh = kd >> 6, d = kd & 63;
        const int dc = d >> 3, dl = d & 7;
#pragma unroll
        for (int r = 0; r < 4; ++r) {
          const int m = m0 + wm + mt * 16 + quad * 4 + r;
          const int bb = m >> 11, s = m & 2047;
          const int t = s >> 6, kr = s & 63;
          const size_t base = ((size_t)((bb * 16 + hh) * 32 + t)) * 8192;
          kv[base + kr * 64 + ((dc ^ (kr & 7)) << 3) + dl] =
              (bf16)((acc[mt][nt][r] + bv) * 1.4426950408889634f);
        }
      }
  } else {
    // V: permuted+swizzled 64-key tile image, 4 tokens per bf16x4
#pragma unroll
    for (int mt = 0; mt < 4; ++mt)
      for (int nt = 0; nt < 4; ++nt) {
        const int n = n0 + wn + nt * 16 + l16;
        const float bv = bias[n];
        const int vd = n - 2048, hh = vd >> 6, d = vd & 63;
        const int m = m0 + wm + mt * 16 + quad * 4;
        const int bb = m >> 11, s = m & 2047;
        const int t = s >> 6, kt = s & 63;
        const int g = kt >> 4, w = kt & 15;
        const int c = 2 * g + ((w >> 2) & 1);
        const int slot = (w & 8) ? 4 : 0;
        const size_t base = ((size_t)((bb * 16 + hh) * 32 + t)) * 8192 + 4096;
        bf16x4 pkv;
#pragma unroll
        for (int r = 0; r < 4; ++r) pkv[r] = (bf16)(acc[mt][nt][r] + bv);
        *(bf16x4*)(kv + base + d * 64 + ((c ^ (d & 7)) << 3) + slot) = pkv;
      }
  }
}

// ---------------- GEMM 128x128 ring3+swz: C = A @ W^T + bias --------------
__global__ __launch_bounds__(256) void gemm_bt(
    const bf16* __restrict__ A, const bf16* __restrict__ W,
    const float* __restrict__ bias,
    float* __restrict__ outF, bf16* __restrict__ outB,
    int M, int N, int K, int nbx) {
  __shared__ bf16 Ab[3][4096];
  __shared__ bf16 Bb[3][4096];
  const int tid = threadIdx.x, lane = tid & 63, wave = tid >> 6;
  const int quad = lane >> 4, l16 = lane & 15;
  int bx, by;
  xcd_map(nbx, nbx * (M >> 7), bx, by);
  const int m0 = by * 128, n0 = bx * 128;
  const int wm = (wave >> 1) * 64, wn = (wave & 1) * 64;
  const int srow = wave * 32 + (lane >> 2);
  const int scol = ((lane & 3) ^ ((lane >> 2) & 3)) * 8;
  const bf16* a0 = A + (size_t)(m0 + srow) * K + scol;
  const bf16* a1 = A + (size_t)(m0 + srow + 16) * K + scol;
  const bf16* w0p = W + (size_t)(n0 + srow) * K + scol;
  const bf16* w1p = W + (size_t)(n0 + srow + 16) * K + scol;
  const int sq = (quad ^ (l16 & 3)) * 8;
  const int nit = K >> 5;
#pragma unroll
  for (int t = 0; t < 2; ++t) {
    gll16(a0 + t * 32, Ab[t] + wave * 1024);
    gll16(a1 + t * 32, Ab[t] + wave * 1024 + 512);
    gll16(w0p + t * 32, Bb[t] + wave * 1024);
    gll16(w1p + t * 32, Bb[t] + wave * 1024 + 512);
  }
  f32x4 acc[4][4] = {};
  int rd = 0, wr = 2;
  for (int g = 0; g < nit; ++g) {
    if (g < nit - 1) asm volatile("s_waitcnt vmcnt(4)" ::: "memory");
    else             asm volatile("s_waitcnt vmcnt(0)" ::: "memory");
    __builtin_amdgcn_s_barrier();
    __builtin_amdgcn_sched_barrier(0);
    if (g + 2 < nit) {
      const int k1 = (g + 2) * 32;
      bf16* da = Ab[wr];
      bf16* db = Bb[wr];
      gll16(a0 + k1, da + wave * 1024);
      gll16(a1 + k1, da + wave * 1024 + 512);
      gll16(w0p + k1, db + wave * 1024);
      gll16(w1p + k1, db + wave * 1024 + 512);
    }
    const bf16* As = Ab[rd];
    const bf16* Bs = Bb[rd];
    bf16x8 af[4], bw[4];
#pragma unroll
    for (int t = 0; t < 4; ++t) {
      af[t] = *(const bf16x8*)(As + (wm + t * 16 + l16) * 32 + sq);
      bw[t] = *(const bf16x8*)(Bs + (wn + t * 16 + l16) * 32 + sq);
    }
    __builtin_amdgcn_s_setprio(1);
#pragma unroll
    for (int mt = 0; mt < 4; ++mt)
#pragma unroll
      for (int nt = 0; nt < 4; ++nt)
        acc[mt][nt] = mfma16(af[mt], bw[nt], acc[mt][nt]);
    __builtin_amdgcn_s_setprio(0);
    rd = (rd + 1 == 3) ? 0 : rd + 1;
    wr = (wr + 1 == 3) ? 0 : wr + 1;
  }
#pragma unroll
  for (int mt = 0; mt < 4; ++mt)
    for (int nt = 0; nt < 4; ++nt) {
      const int n = n0 + wn + nt * 16 + l16;
      const float bv = bias ? bias[n] : 0.0f;
#pragma unroll
      for (int r = 0; r < 4; ++r) {
        const int m = m0 + wm + mt * 16 + quad * 4 + r;
        const float v = acc[mt][nt][r] + bv;
        if (outF) outF[(size_t)m * N + n] = v;
        if (outB) outB[(size_t)m * N + n] = (bf16)v;
      }
    }
}

// ---------------- GEMM 128x64 ring3+swz (out-proj) ----------------
__global__ __launch_bounds__(256) void gemm_bt64(
    const bf16* __restrict__ A, const bf16* __restrict__ W,
    const float* __restrict__ bias, float* __restrict__ outF,
    int M, int N, int K) {
  __shared__ bf16 Ab[3][4096];
  __shared__ bf16 Bb[3][2048];
  const int tid = threadIdx.x, lane = tid & 63, wave = tid >> 6;
  const int quad = lane >> 4, l16 = lane & 15;
  int bx, by;
  xcd_map(16, 16 * 32, bx, by);
  const int m0 = by * 128, n0 = bx * 64;
  const int wm = (wave >> 1) * 64, wn = (wave & 1) * 32;
  const int srow = wave * 32 + (lane >> 2);
  const int srowB = wave * 16 + (lane >> 2);
  const int scol = ((lane & 3) ^ ((lane >> 2) & 3)) * 8;
  const bf16* a0 = A + (size_t)(m0 + srow) * K + scol;
  const bf16* a1 = A + (size_t)(m0 + srow + 16) * K + scol;
  const bf16* w0p = W + (size_t)(n0 + srowB) * K + scol;
  const int sq = (quad ^ (l16 & 3)) * 8;
  const int nit = K >> 5;
#pragma unroll
  for (int t = 0; t < 2; ++t) {
    gll16(a0 + t * 32, Ab[t] + wave * 1024);
    gll16(a1 + t * 32, Ab[t] + wave * 1024 + 512);
    gll16(w0p + t * 32, Bb[t] + wave * 512);
  }
  f32x4 acc[4][2] = {};
  int rd = 0, wr = 2;
  for (int g = 0; g < nit; ++g) {
    if (g < nit - 1) asm volatile("s_waitcnt vmcnt(3)" ::: "memory");
    else             asm volatile("s_waitcnt vmcnt(0)" ::: "memory");
    __builtin_amdgcn_s_barrier();
    __builtin_amdgcn_sched_barrier(0);
    if (g + 2 < nit) {
      const int k1 = (g + 2) * 32;
      gll16(a0 + k1, Ab[wr] + wave * 1024);
      gll16(a1 + k1, Ab[wr] + wave * 1024 + 512);
      gll16(w0p + k1, Bb[wr] + wave * 512);
    }
    const bf16* As = Ab[rd];
    const bf16* Bs = Bb[rd];
    bf16x8 af[4], bw[2];
#pragma unroll
    for (int t = 0; t < 4; ++t)
      af[t] = *(const bf16x8*)(As + (wm + t * 16 + l16) * 32 + sq);
#pragma unroll
    for (int t = 0; t < 2; ++t)
      bw[t] = *(const bf16x8*)(Bs + (wn + t * 16 + l16) * 32 + sq);
    __builtin_amdgcn_s_setprio(1);
#pragma unroll
    for (int mt = 0; mt < 4; ++mt)
#pragma unroll
      for (int nt = 0; nt < 2; ++nt)
        acc[mt][nt] = mfma16(af[mt], bw[nt], acc[mt][nt]);
    __builtin_amdgcn_s_setprio(0);
    rd = (rd + 1 == 3) ? 0 : rd + 1;
    wr = (wr + 1 == 3) ? 0 : wr + 1;
  }
#pragma unroll
  for (int mt = 0; mt < 4; ++mt)
    for (int nt = 0; nt < 2; ++nt) {
      const int n = n0 + wn + nt * 16 + l16;
      const float bv = bias[n];
#pragma unroll
      for (int r = 0; r < 4; ++r) {
        const int m = m0 + wm + mt * 16 + quad * 4 + r;
        outF[(size_t)m * N + n] = acc[mt][nt][r] + bv;
      }
    }
}

// ---------------- flash attention v14: dual-stream + counted vmcnt ---------
__global__ __launch_bounds__(256, 2) void attn14(
    const bf16* __restrict__ Q, const bf16* __restrict__ KV,
    bf16* __restrict__ ctx) {
  __shared__ __align__(16) bf16 kvb[2][16384];  // [buf][2 x (K 4096 | V 4096)]
  __shared__ float Linv[4][32];
  const int tid = threadIdx.x, lane = tid & 63, wave = tid >> 6;
  const int hi = lane >> 5, l31 = lane & 31, l7 = lane & 7;
  const int bid = blockIdx.x;
  const int hb = (bid & 7) * 4 + ((bid >> 3) & 3);
  const int qt = bid >> 5;              // 0..15
  const int h = hb & 15, b = hb >> 4;

  bf16x8 qf[4];
  {
    const int qrow = qt * 128 + wave * 32 + l31;
    const bf16* qp = Q + (size_t)(b * SEQ + qrow) * 1024 + h * HD + hi * 8;
#pragma unroll
    for (int t = 0; t < 4; ++t) qf[t] = *(const bf16x8*)(qp + t * 16);
  }
  asm volatile("s_waitcnt vmcnt(0)" ::: "memory");

  const int soff = tid * 8;
  const bf16* kvg = KV + ((size_t)(b * NH + h) * 32) * 8192 + soff;
#pragma unroll
  for (int i = 0; i < 8; ++i)
    gll16(kvg + i * 2048, kvb[0] + soff + i * 2048);
#pragma unroll
  for (int i = 0; i < 8; ++i)
    gll16(kvg + 16384 + i * 2048, kvb[1] + soff + i * 2048);

  f32x16 o0 = {}, o1 = {};
  float lpart = 0.0f;
  const f32x16 zf = {};

  for (int t = 0; t < 16; ++t) {
    if (t < 15) asm volatile("s_waitcnt vmcnt(8)" ::: "memory");
    else        asm volatile("s_waitcnt vmcnt(0)" ::: "memory");
    __builtin_amdgcn_s_barrier();
    __builtin_amdgcn_sched_barrier(0);
    const bf16* tb = kvb[t & 1];
#pragma unroll
    for (int half = 0; half < 2; ++half) {
      const bf16* ks = tb + half * 8192;
      const bf16* vs = ks + 4096;
      f32x16 s0, s1;
      __builtin_amdgcn_s_setprio(1);
      {
        const int swc = (hi ^ l7) * 8;
        bf16x8 k0 = *(const bf16x8*)(ks + l31 * 64 + swc);
        bf16x8 k1 = *(const bf16x8*)(ks + (32 + l31) * 64 + swc);
        s0 = mfma32(k0, qf[0], zf);
        s1 = mfma32(k1, qf[0], zf);
      }
#pragma unroll
      for (int tt = 1; tt < 4; ++tt) {
        const int swc = ((tt * 2 + hi) ^ l7) * 8;
        bf16x8 k0 = *(const bf16x8*)(ks + l31 * 64 + swc);
        bf16x8 k1 = *(const bf16x8*)(ks + (32 + l31) * 64 + swc);
        s0 = mfma32(k0, qf[tt], s0);
        s1 = mfma32(k1, qf[tt], s1);
      }
      __builtin_amdgcn_s_setprio(0);
      unsigned u[16];
#pragma unroll
      for (int g = 0; g < 8; ++g) {
        const int base = (g & 3) * 4;
        float e0, e1, e2, e3;
        if (g < 4) {
          e0 = __builtin_amdgcn_exp2f(s0[base]);
          e1 = __builtin_amdgcn_exp2f(s0[base + 1]);
          e2 = __builtin_amdgcn_exp2f(s0[base + 2]);
          e3 = __builtin_amdgcn_exp2f(s0[base + 3]);
        } else {
          e0 = __builtin_amdgcn_exp2f(s1[base]);
          e1 = __builtin_amdgcn_exp2f(s1[base + 1]);
          e2 = __builtin_amdgcn_exp2f(s1[base + 2]);
          e3 = __builtin_amdgcn_exp2f(s1[base + 3]);
        }
        lpart += (e0 + e1) + (e2 + e3);
        u[g * 2] = pk2(e0, e1);
        u[g * 2 + 1] = pk2(e2, e3);
      }
      __builtin_amdgcn_s_setprio(1);
#pragma unroll
      for (int kk = 0; kk < 4; ++kk) {
        union { unsigned w[4]; bf16x8 v; } fw;
        fw.w[0] = u[4 * kk]; fw.w[1] = u[4 * kk + 1];
        fw.w[2] = u[4 * kk + 2]; fw.w[3] = u[4 * kk + 3];
        const int c16 = (2 * kk + hi) ^ l7;
        bf16x8 v0 = *(const bf16x8*)(vs + l31 * 64 + c16 * 8);
        bf16x8 v1 = *(const bf16x8*)(vs + (32 + l31) * 64 + c16 * 8);
        o0 = mfma32(fw.v, v0, o0);
        o1 = mfma32(fw.v, v1, o1);
      }
      __builtin_amdgcn_s_setprio(0);
    }
    __builtin_amdgcn_sched_barrier(0);
    __builtin_amdgcn_s_barrier();
    __builtin_amdgcn_sched_barrier(0);
    if (t + 2 < 16) {
      const bf16* src = kvg + (size_t)(t + 2) * 16384;
      bf16* dst = kvb[t & 1] + soff;
#pragma unroll
      for (int i = 0; i < 8; ++i) gll16(src + i * 2048, dst + i * 2048);
    }
  }
  float ltot = lpart + __shfl_xor(lpart, 32, 64);
  if (lane < 32) Linv[wave][lane] = 1.0f / ltot;
#pragma unroll
  for (int r = 0; r < 16; ++r) {
    const int qloc = (r & 3) + 8 * (r >> 2) + 4 * hi;
    const float inv = Linv[wave][qloc];
    const int qrow = qt * 128 + wave * 32 + qloc;
    bf16* cp = ctx + (size_t)(b * SEQ + qrow) * EMB + h * HD;
    cp[l31] = (bf16)(o0[r] * inv);
    cp[32 + l31] = (bf16)(o1[r] * inv);
  }
}

// ---------------- residual + LayerNorm ----------------
__global__ __launch_bounds__(256) void ln1_k(
    const float* __restrict__ x, const float* __restrict__ ao,
    const float* __restrict__ g, const float* __restrict__ bta,
    float* __restrict__ hF, bf16* __restrict__ hB) {
  int row = blockIdx.x, tid = threadIdx.x;
  const float* xr = x + (size_t)row * EMB;
  const float* ar = ao + (size_t)row * EMB;
  float v[4], s = 0.0f, s2 = 0.0f;
#pragma unroll
  for (int i = 0; i < 4; ++i) {
    float t = xr[tid + i * 256] + ar[tid + i * 256];
    v[i] = t; s += t; s2 += t * t;
  }
#pragma unroll
  for (int off = 1; off < 64; off <<= 1) {
    s += __shfl_xor(s, off, 64);
    s2 += __shfl_xor(s2, off, 64);
  }
  __shared__ float red[8];
  int wave = tid >> 6, lane = tid & 63;
  if (lane == 0) { red[wave] = s; red[4 + wave] = s2; }
  __syncthreads();
  s = red[0] + red[1] + red[2] + red[3];
  s2 = red[4] + red[5] + red[6] + red[7];
  float mean = s * (1.0f / EMB);
  float var = s2 * (1.0f / EMB) - mean * mean;
  float inv = rsqrtf(var + 1e-5f);
#pragma unroll
  for (int i = 0; i < 4; ++i) {
    int c = tid + i * 256;
    float t = (v[i] - mean) * inv * g[c] + bta[c];
    hF[(size_t)row * EMB + c] = t;
    hB[(size_t)row * EMB + c] = (bf16)t;
  }
}

__global__ __launch_bounds__(256) void geglu_ln2(
    const float* __restrict__ h, const bf16* __restrict__ proj,
    const float* __restrict__ g, const float* __restrict__ bta,
    float* __restrict__ out) {
  int row = blockIdx.x, tid = threadIdx.x;
  const float* hr = h + (size_t)row * EMB;
  const bf16* pr = proj + (size_t)row * 2048;
  float v[4], s = 0.0f, s2 = 0.0f;
#pragma unroll
  for (int i = 0; i < 4; ++i) {
    int c = tid + i * 256;
    float val = (float)pr[c];
    float gate = (float)pr[1024 + c];
    float ge = 0.5f * gate * (1.0f + erff(gate * 0.70710678f));
    float t = hr[c] + val * ge;
    v[i] = t; s += t; s2 += t * t;
  }
#pragma unroll
  for (int off = 1; off < 64; off <<= 1) {
    s += __shfl_xor(s, off, 64);
    s2 += __shfl_xor(s2, off, 64);
  }
  __shared__ float red[8];
  int wave = tid >> 6, lane = tid & 63;
  if (lane == 0) { red[wave] = s; red[4 + wave] = s2; }
  __syncthreads();
  s = red[0] + red[1] + red[2] + red[3];
  s2 = red[4] + red[5] + red[6] + red[7];
  float mean = s * (1.0f / EMB);
  float var = s2 * (1.0f / EMB) - mean * mean;
  float inv = rsqrtf(var + 1e-5f);
#pragma unroll
  for (int i = 0; i < 4; ++i) {
    int c = tid + i * 256;
    out[(size_t)row * EMB + c] = (v[i] - mean) * inv * g[c] + bta[c];
  }
}

extern "C" void kernel_launch(void* const* d_in, const int* in_sizes, int n_in,
                              void* d_out, int out_size, void* d_ws, size_t ws_size,
                              hipStream_t stream) {
  const float* x = (const float*)d_in[0];
  const float* inW = (const float*)d_in[1];
  const float* inB = (const float*)d_in[2];
  const float* outW = (const float*)d_in[3];
  const float* opB = (const float*)d_in[4];
  const float* ggW = (const float*)d_in[5];
  const float* ggB = (const float*)d_in[6];
  const float* g1 = (const float*)d_in[7];
  const float* b1 = (const float*)d_in[8];
  const float* g2 = (const float*)d_in[9];
  const float* b2 = (const float*)d_in[10];
  float* out = (float*)d_out;
  char* ws = (char*)d_ws;
  const size_t MB = 1ull << 20;
  bf16* xb = (bf16*)(ws);              // 8 MB, dead after gemm_in
  bf16* hB = (bf16*)(ws);              // overlays xb (ln1 out)
  bf16* qr = (bf16*)(ws + 8 * MB);     // 8 MB, dead after gemm_in
  bf16* ctx = (bf16*)(ws + 8 * MB);    // overlays qr (attn output)
  bf16* wI = (bf16*)(ws + 16 * MB);    // 6 MB
  bf16* wO = (bf16*)(ws + 22 * MB);    // 2 MB
  bf16* wG = (bf16*)(ws + 24 * MB);    // 4 MB
  bf16* qb = (bf16*)(ws + 28 * MB);    // 8 MB, dead after attn
  bf16* kv = (bf16*)(ws + 36 * MB);    // 16 MB tile images, dead after attn
  bf16* projB = (bf16*)(ws + 28 * MB); // overlays qb+kv (GeGLU proj)
  float* ao = (float*)(ws + 52 * MB);  // 16 MB f32

  prep_all<<<8192 + 6144, 256, 0, stream>>>(x, xb, qr, inW, outW, ggW,
                                            wI, wO, wG);
  gemm_in<<<dim3(24, 32), 256, 0, stream>>>(qr, xb, wI, inB, qb, kv);
  attn14<<<512, 256, 0, stream>>>(qb, kv, ctx);
  gemm_bt64<<<dim3(16, 32), 256, 0, stream>>>(ctx, wO, opB, ao,
                                              NTOK, 1024, 1024);
  ln1_k<<<NTOK, 256, 0, stream>>>(x, ao, g1, b1, ao, hB);
  gemm_bt<<<dim3(16, 32), 256, 0, stream>>>(hB, wG, ggB, nullptr, projB,
                                            NTOK, 2048, 1024, 16);
  geglu_ln2<<<NTOK, 256, 0, stream>>>(ao, projB, g2, b2, out);
}